// Round 1
// baseline (3351.531 us; speedup 1.0000x reference)
//
#include <hip/hip_runtime.h>
#include <cstdint>
#include <cstddef>

#define NN 25
#define BB 4096
#define DD 1024
#define CHEB_M 24

typedef __attribute__((ext_vector_type(8))) short bf16x8;
typedef __attribute__((ext_vector_type(4))) float f32x4;

static __device__ __forceinline__ float bf2f(uint16_t u) {
    return __uint_as_float(((uint32_t)u) << 16);
}
static __device__ __forceinline__ uint16_t f2bf(float f) {
    uint32_t u = __float_as_uint(f);
    return (uint16_t)((u + 0x7FFFu + ((u >> 16) & 1u)) >> 16);
}
static __device__ __forceinline__ float gelu_f(float x) {
    return 0.5f * x * (1.0f + erff(x * 0.70710678118654752440f));
}
static __device__ __forceinline__ void gload16(const void* g, void* l) {
    __builtin_amdgcn_global_load_lds((const __attribute__((address_space(1))) void*)g,
                                     (__attribute__((address_space(3))) void*)l,
                                     16, 0, 0);
}
static __device__ __forceinline__ uint32_t wang(uint32_t s) {
    s = (s ^ 61u) ^ (s >> 16); s *= 9u; s ^= s >> 4; s *= 0x27d4eb2du; s ^= s >> 15;
    return s;
}

// ---------------------------------------------------------------------------
// prep_x: x[b][n][d] fp32 -> xb[n][b][d] bf16 (node-major for contiguous GEMM A)
// grid: BB*NN blocks, 256 threads
__global__ void k_prep_x(const float* __restrict__ x, uint16_t* __restrict__ xb) {
    const int r = blockIdx.x;           // 0..BB*NN-1
    const int b = r / NN, n = r % NN;
    const float* src = x + (size_t)r * DD;
    uint16_t* dst = xb + ((size_t)n * BB + b) * DD;
    const int t = threadIdx.x;
    float4 v = ((const float4*)src)[t];
    ushort4 o;
    o.x = f2bf(v.x); o.y = f2bf(v.y); o.z = f2bf(v.z); o.w = f2bf(v.w);
    ((ushort4*)dst)[t] = o;
}

// ---------------------------------------------------------------------------
// prep_w: W[n][i][o] fp32 -> Wtb[slab][o][i] bf16 (transposed) + per-node ||W||_F^2
// grid: (16,16,25), 256 threads
__global__ void k_prep_w(const float* __restrict__ W, uint16_t* __restrict__ Wtb,
                         float* __restrict__ F2, int slab_base) {
    const int n = blockIdx.z;
    const float* Wn = W + (size_t)n * DD * DD;
    uint16_t* Tn = Wtb + (size_t)(slab_base + n) * DD * DD;
    const int i0 = blockIdx.y * 64, o0 = blockIdx.x * 64;
    __shared__ float tile[64][65];
    const int t = threadIdx.x;
    const int cr = t >> 6;     // 0..3
    const int cc = t & 63;     // 0..63
    float acc = 0.f;
    #pragma unroll
    for (int p = 0; p < 16; ++p) {
        const int row = p * 4 + cr;
        float v = Wn[(size_t)(i0 + row) * DD + o0 + cc];
        tile[row][cc] = v;
        acc += v * v;
    }
    __syncthreads();
    #pragma unroll
    for (int p = 0; p < 16; ++p) {
        const int orow = p * 4 + cr;
        Tn[(size_t)(o0 + orow) * DD + i0 + cc] = f2bf(tile[cc][orow]);
    }
    #pragma unroll
    for (int sh = 32; sh; sh >>= 1) acc += __shfl_down(acc, sh);
    if ((t & 63) == 0) atomicAdd(&F2[slab_base + n], acc);
}

// ---------------------------------------------------------------------------
// Unified bf16 MFMA GEMM: C = A * Bt^T per node slab (m97 structure).
// MODE 0: C bf16 (B-forming, no scale/bias)
// MODE 1: C bf16 = gelu(acc*inv_s + bias)  (hidden layer, node-major)
// MODE 2: C fp32 = acc*inv_s + bias, strided [b][n][o] store to d_out
template <int MODE>
__global__ void k_gemm(const uint16_t* __restrict__ A, size_t sA,
                       const uint16_t* __restrict__ Bt, size_t sB,
                       void* __restrict__ Cp, size_t sC,
                       const float* __restrict__ inv_sigma, int sig_base,
                       const float* __restrict__ bias) {
    const int z = blockIdx.z;
    const uint16_t* An = A + (size_t)z * sA;
    const uint16_t* Bn = Bt + (size_t)z * sB;
    const int m0 = blockIdx.y * 128;
    const int n0 = blockIdx.x * 128;
    __shared__ __align__(16) uint16_t Alds[128 * 32];
    __shared__ __align__(16) uint16_t Blds[128 * 32];
    const int tid  = threadIdx.x;
    const int wave = tid >> 6;
    const int lane = tid & 63;
    const int quad = lane >> 4;
    const int l16  = lane & 15;
    const int wm = wave >> 1;
    const int wn = wave & 1;

    f32x4 acc[4][4];
    #pragma unroll
    for (int i = 0; i < 4; ++i)
        #pragma unroll
        for (int j = 0; j < 4; ++j)
            acc[i][j] = (f32x4){0.f, 0.f, 0.f, 0.f};

    for (int k0 = 0; k0 < DD; k0 += 32) {
        __syncthreads();
        #pragma unroll
        for (int c = 0; c < 2; ++c) {
            const int p = (c * 4 + wave) * 64 + lane;   // 0..511 chunk id
            const int row = p >> 2, seg = p & 3;
            gload16(An + (size_t)(m0 + row) * DD + (k0 + seg * 8), &Alds[p * 8]);
            gload16(Bn + (size_t)(n0 + row) * DD + (k0 + seg * 8), &Blds[p * 8]);
        }
        __syncthreads();
        bf16x8 af[4], bfv[4];
        #pragma unroll
        for (int i = 0; i < 4; ++i) {
            af[i]  = *(const bf16x8*)&Alds[(wm * 64 + i * 16 + l16) * 32 + quad * 8];
            bfv[i] = *(const bf16x8*)&Blds[(wn * 64 + i * 16 + l16) * 32 + quad * 8];
        }
        #pragma unroll
        for (int i = 0; i < 4; ++i)
            #pragma unroll
            for (int j = 0; j < 4; ++j)
                acc[i][j] = __builtin_amdgcn_mfma_f32_16x16x32_bf16(af[i], bfv[j],
                                                                    acc[i][j], 0, 0, 0);
    }

    float inv_s = 1.0f;
    if (MODE != 0) inv_s = inv_sigma[sig_base + z];
    #pragma unroll
    for (int i = 0; i < 4; ++i) {
        const int rbase = m0 + wm * 64 + i * 16 + quad * 4;
        #pragma unroll
        for (int j = 0; j < 4; ++j) {
            const int col = n0 + wn * 64 + j * 16 + l16;
            float bv = 0.f;
            if (MODE != 0) bv = bias[z * DD + col];
            #pragma unroll
            for (int r = 0; r < 4; ++r) {
                const int row = rbase + r;
                float v = acc[i][j][r];
                if (MODE == 0) {
                    ((uint16_t*)Cp)[(size_t)z * sC + (size_t)row * DD + col] = f2bf(v);
                } else if (MODE == 1) {
                    v = gelu_f(v * inv_s + bv);
                    ((uint16_t*)Cp)[(size_t)z * sC + (size_t)row * DD + col] = f2bf(v);
                } else {
                    ((float*)Cp)[((size_t)row * NN + z) * DD + col] = v * inv_s + bv;
                }
            }
        }
    }
}

// ---------------------------------------------------------------------------
// Chebyshev-filtered iteration on B (bf16, symmetric), interval [-0.02,0.93]*lam_hat.
// One 1024-thread block per node; 2 independent start vectors.
__global__ void __launch_bounds__(1024) k_cheb(const uint16_t* __restrict__ Ball,
                                               const float* __restrict__ F2,
                                               float* __restrict__ vout,
                                               float* __restrict__ rden) {
    const int nb = blockIdx.x;                     // 0..49
    const uint16_t* Bc = Ball + (size_t)nb * DD * DD;
    __shared__ float cur0[DD], cur1[DD], prev0[DD], prev1[DD];
    const int t = threadIdx.x;
    const float lam = 4.0f * F2[nb] * (1.0f / 1024.0f);   // MP edge estimate of lambda1
    const float hi = 0.93f * lam, lo = -0.02f * lam;
    const float w = hi - lo, s = hi + lo;
    const float invw = 1.0f / w;
    const float v00 = (wang(nb * 4096 + t) & 1u) ? 1.f : -1.f;
    const float v01 = (wang(nb * 4096 + 2048 + t) & 1u) ? 1.f : -1.f;
    prev0[t] = v00; prev1[t] = v01;
    __syncthreads();
    {   // t1 = M v0
        float y0 = 0.f, y1 = 0.f;
        const uint16_t* bp = Bc + t;
        for (int o = 0; o < DD; ++o) {
            const float bb = bf2f(bp[(size_t)o * DD]);    // B[o][t] == B[t][o]
            y0 = fmaf(bb, prev0[o], y0);
            y1 = fmaf(bb, prev1[o], y1);
        }
        cur0[t] = (2.f * y0 - s * v00) * invw;
        cur1[t] = (2.f * y1 - s * v01) * invw;
    }
    for (int it = 1; it < CHEB_M; ++it) {
        __syncthreads();
        float y0 = 0.f, y1 = 0.f;
        const uint16_t* bp = Bc + t;
        for (int o = 0; o < DD; ++o) {
            const float bb = bf2f(bp[(size_t)o * DD]);
            y0 = fmaf(bb, cur0[o], y0);
            y1 = fmaf(bb, cur1[o], y1);
        }
        const float n0 = (4.f * y0 - 2.f * s * cur0[t]) * invw - prev0[t];
        const float n1 = (4.f * y1 - 2.f * s * cur1[t]) * invw - prev1[t];
        __syncthreads();
        prev0[t] = cur0[t]; prev1[t] = cur1[t];
        cur0[t] = n0; cur1[t] = n1;
    }
    __syncthreads();
    const float c0 = cur0[t], c1 = cur1[t];
    vout[((size_t)nb * 2 + 0) * DD + t] = c0;
    vout[((size_t)nb * 2 + 1) * DD + t] = c1;
    float d0 = c0 * c0, d1 = c1 * c1;
    #pragma unroll
    for (int sh = 32; sh; sh >>= 1) { d0 += __shfl_down(d0, sh); d1 += __shfl_down(d1, sh); }
    if ((t & 63) == 0) { atomicAdd(&rden[nb * 2], d0); atomicAdd(&rden[nb * 2 + 1], d1); }
}

// ---------------------------------------------------------------------------
// Rayleigh: rnum[nb][j] = ||W v_j||^2 with ORIGINAL fp32 W. grid (16, 50), 256 thr.
__global__ void k_rayleigh(const float* __restrict__ W1, const float* __restrict__ W2,
                           const float* __restrict__ vout, float* __restrict__ rnum) {
    const int nb = blockIdx.y;
    const int bi = blockIdx.x;
    const float* Wn = (nb < NN) ? (W1 + (size_t)nb * DD * DD)
                                : (W2 + (size_t)(nb - NN) * DD * DD);
    __shared__ float v0[DD], v1[DD];
    const int t = threadIdx.x;
    #pragma unroll
    for (int c = 0; c < 4; ++c) {
        v0[t + 256 * c] = vout[((size_t)nb * 2 + 0) * DD + t + 256 * c];
        v1[t + 256 * c] = vout[((size_t)nb * 2 + 1) * DD + t + 256 * c];
    }
    __syncthreads();
    const int wv = t >> 6, lane = t & 63;
    float a0 = 0.f, a1 = 0.f;
    for (int g = 0; g < 16; ++g) {
        const int row = bi * 64 + g * 4 + wv;
        const float* Wr = Wn + (size_t)row * DD;
        float p0 = 0.f, p1 = 0.f;
        #pragma unroll
        for (int c = 0; c < 16; ++c) {
            const float wval = Wr[lane + 64 * c];
            p0 = fmaf(wval, v0[lane + 64 * c], p0);
            p1 = fmaf(wval, v1[lane + 64 * c], p1);
        }
        #pragma unroll
        for (int sh = 32; sh; sh >>= 1) { p0 += __shfl_down(p0, sh); p1 += __shfl_down(p1, sh); }
        if (lane == 0) { a0 += p0 * p0; a1 += p1 * p1; }
    }
    if (lane == 0) { atomicAdd(&rnum[nb * 2], a0); atomicAdd(&rnum[nb * 2 + 1], a1); }
}

__global__ void k_finalize(const float* __restrict__ rnum, const float* __restrict__ rden,
                           float* __restrict__ inv_sigma) {
    const int t = threadIdx.x;
    if (t < 50) {
        const float q0 = rnum[2 * t] / rden[2 * t];
        const float q1 = rnum[2 * t + 1] / rden[2 * t + 1];
        inv_sigma[t] = rsqrtf(fmaxf(q0, q1));   // 1/sigma
    }
}

// ---------------------------------------------------------------------------
extern "C" void kernel_launch(void* const* d_in, const int* in_sizes, int n_in,
                              void* d_out, int out_size, void* d_ws, size_t ws_size,
                              hipStream_t stream) {
    (void)in_sizes; (void)n_in; (void)out_size; (void)ws_size;
    const float* x  = (const float*)d_in[0];
    const float* w1 = (const float*)d_in[1];
    const float* b1 = (const float*)d_in[2];
    const float* w2 = (const float*)d_in[3];
    const float* b2 = (const float*)d_in[4];

    // Workspace layout (~315 MB):
    char* ws = (char*)d_ws;
    uint16_t* wtb = (uint16_t*)ws;                                   // 50*1M bf16 = 104857600 B
    uint16_t* hb  = (uint16_t*)(ws + 104857600);                     // 25*4096*1024 bf16 = 209715200 B
    float* vout   = (float*)(ws + 104857600 + 209715200);            // 50*2*1024 f32 = 409600 B
    float* scal   = (float*)(ws + 104857600 + 209715200 + 409600);   // scalars
    float* F2        = scal;         // [50]
    float* rnum      = scal + 64;    // [100]
    float* rden      = scal + 192;   // [100]
    float* inv_sigma = scal + 320;   // [50]

    // d_out doubles as scratch (dead before GEMM2 writes it):
    uint16_t* xb  = (uint16_t*)d_out;                          // 209715200 B
    uint16_t* Bws = (uint16_t*)((char*)d_out + 209715200);     // 104857600 B

    hipMemsetAsync(scal, 0, 512 * sizeof(float), stream);

    k_prep_x<<<BB * NN, 256, 0, stream>>>(x, xb);
    k_prep_w<<<dim3(16, 16, NN), 256, 0, stream>>>(w1, wtb, F2, 0);
    k_prep_w<<<dim3(16, 16, NN), 256, 0, stream>>>(w2, wtb, F2, NN);

    // B = W^T W  (A = Wt, Bt = Wt), 50 nodes, M=N=K=1024
    k_gemm<0><<<dim3(8, 8, 50), 256, 0, stream>>>(
        wtb, (size_t)1048576, wtb, (size_t)1048576,
        (void*)Bws, (size_t)1048576, nullptr, 0, nullptr);

    k_cheb<<<50, 1024, 0, stream>>>(Bws, F2, vout, rden);
    k_rayleigh<<<dim3(16, 50), 256, 0, stream>>>(w1, w2, vout, rnum);
    k_finalize<<<1, 64, 0, stream>>>(rnum, rden, inv_sigma);

    // h = gelu(x*W1 * inv_s1 + b1)   (node-major bf16)
    k_gemm<1><<<dim3(8, 32, NN), 256, 0, stream>>>(
        xb, (size_t)BB * DD, wtb, (size_t)1048576,
        (void*)hb, (size_t)BB * DD, inv_sigma, 0, b1);

    // out = h*W2 * inv_s2 + b2   (fp32, [b][n][o] strided store)
    k_gemm<2><<<dim3(8, 32, NN), 256, 0, stream>>>(
        hb, (size_t)BB * DD, wtb + (size_t)NN * 1048576, (size_t)1048576,
        d_out, 0, inv_sigma, NN, b2);
}